// Round 1
// baseline (1092.121 us; speedup 1.0000x reference)
//
#include <hip/hip_runtime.h>
#include <hip/hip_cooperative_groups.h>
#include <stdint.h>

namespace cg = cooperative_groups;

#define D_MODEL 2048
#define N_ROOMS 128
#define BATCH   128
#define SEQ     512
#define NN      (N_ROOMS * N_ROOMS)   // 16384
#define NCOL    (NN + N_ROOMS)        // 16512
#define KSW     4                     // warp-gemm K-split (fused path)

typedef short bf16x8 __attribute__((ext_vector_type(8)));
typedef float f32x4  __attribute__((ext_vector_type(4)));

__device__ __forceinline__ unsigned short f2bf(float f) {
    union { float f; uint32_t u; } c; c.f = f;
    uint32_t u = c.u;
    uint32_t r = (u + 0x7fffu + ((u >> 16) & 1u)) >> 16;  // RNE
    return (unsigned short)r;
}

// ============================================================================
// Fused cooperative megakernel: mean -> ctx GEMM -> warp GEMM -> epilogue
// grid-stride phases; grid must be co-resident (cooperative launch).
// ============================================================================
__launch_bounds__(256, 4)
__global__ void k_fused(const float* __restrict__ x,
                        const float* __restrict__ room,
                        const float* __restrict__ Wc,
                        const float* __restrict__ bc,
                        const float* __restrict__ Ww,
                        const float* __restrict__ bw,
                        const float* __restrict__ adj,
                        float* __restrict__ out,
                        float* __restrict__ part,
                        unsigned short* __restrict__ meanb,
                        float* __restrict__ ctx_part,
                        unsigned short* __restrict__ ctxb,
                        float* __restrict__ wp) {
    cg::grid_group gg = cg::this_grid();
    __shared__ short A[128 * 72];
    __shared__ short Bt[64 * 72];
    const int tid = threadIdx.x, lane = tid & 63, w = tid >> 6;
    const int nb = gridDim.x, bid = blockIdx.x;

    // ---- P1: partial mean over S. 1024 units (b x sc); each block streams a
    // fully contiguous 512 KB chunk (64 seq rows of one b).
    for (int u = bid; u < BATCH * 8; u += nb) {
        int b = u >> 3, sc = u & 7;
        const float* p = x + ((size_t)(b * SEQ + sc * 64)) * D_MODEL;
        float ax = 0.f, ay = 0.f, az = 0.f, aw = 0.f;
        float cx = 0.f, cy = 0.f, cz = 0.f, cw = 0.f;
        #pragma unroll 4
        for (int s = 0; s < 64; ++s) {
            float4 v0 = *(const float4*)(p + (size_t)s * D_MODEL + tid * 4);
            float4 v1 = *(const float4*)(p + (size_t)s * D_MODEL + 1024 + tid * 4);
            ax += v0.x; ay += v0.y; az += v0.z; aw += v0.w;
            cx += v1.x; cy += v1.y; cz += v1.z; cw += v1.w;
        }
        float* q = part + ((size_t)(sc * BATCH + b)) * D_MODEL;
        float4 o0 = {ax, ay, az, aw};
        float4 o1 = {cx, cy, cz, cw};
        *(float4*)(q + tid * 4) = o0;
        *(float4*)(q + 1024 + tid * 4) = o1;
    }
    gg.sync();

    // ---- P2: combine partials -> meanb (bf16). 256 units.
    for (int u = bid; u < 256; u += nb) {
        int i = (u * 256 + tid) * 4;
        float4 s = {0.f, 0.f, 0.f, 0.f};
        #pragma unroll
        for (int sc = 0; sc < 8; ++sc) {
            float4 v = *(const float4*)(part + (size_t)sc * BATCH * D_MODEL + i);
            s.x += v.x; s.y += v.y; s.z += v.z; s.w += v.w;
        }
        const float inv = 1.0f / (float)SEQ;
        ushort4 hv = {f2bf(s.x * inv), f2bf(s.y * inv), f2bf(s.z * inv), f2bf(s.w * inv)};
        *(ushort4*)(meanb + i) = hv;
    }
    gg.sync();

    // ---- P3: ctx GEMM  C[b][d] = sum_k mean[b][k]*Wc[d][k]. 256 units
    // (32 n-tiles x 8 k-splits), tile 128x64, BK=64.
    for (int u = bid; u < 256; u += nb) {
        int nt = u & 31, ks = u >> 5;
        int n0 = nt * 64, k0 = ks * 256;
        int mbase = w * 32;
        f32x4 acc[2][4] = {};
        for (int kt = 0; kt < 4; ++kt) {
            int kb = k0 + kt * 64;
            __syncthreads();
            #pragma unroll
            for (int i = 0; i < 4; ++i) {            // A: 128 x 64 bf16
                int uu = tid + 256 * i;
                int row = uu >> 3, c = uu & 7;
                *(int4*)&A[row * 72 + c * 8] =
                    *(const int4*)(meanb + (size_t)row * D_MODEL + kb + c * 8);
            }
            #pragma unroll
            for (int i = 0; i < 4; ++i) {            // B: 64 x 64 fp32 -> bf16
                int uu = tid + 256 * i;
                int row = uu >> 4, c = uu & 15;
                float4 v = *(const float4*)(Wc + (size_t)(n0 + row) * D_MODEL + kb + c * 4);
                ushort4 hv = {f2bf(v.x), f2bf(v.y), f2bf(v.z), f2bf(v.w)};
                *(ushort4*)&Bt[row * 72 + c * 4] = hv;
            }
            __syncthreads();
            #pragma unroll
            for (int kk = 0; kk < 64; kk += 32) {
                int ko = kk + (lane >> 4) * 8;
                int mr = mbase + (lane & 15);
                bf16x8 a0 = *(const bf16x8*)&A[mr * 72 + ko];
                bf16x8 a1 = *(const bf16x8*)&A[(mr + 16) * 72 + ko];
                #pragma unroll
                for (int ni = 0; ni < 4; ++ni) {
                    bf16x8 bfr = *(const bf16x8*)&Bt[(ni * 16 + (lane & 15)) * 72 + ko];
                    acc[0][ni] = __builtin_amdgcn_mfma_f32_16x16x32_bf16(a0, bfr, acc[0][ni], 0, 0, 0);
                    acc[1][ni] = __builtin_amdgcn_mfma_f32_16x16x32_bf16(a1, bfr, acc[1][ni], 0, 0, 0);
                }
            }
        }
        int col = lane & 15, quad = lane >> 4;
        #pragma unroll
        for (int mi = 0; mi < 2; ++mi)
            #pragma unroll
            for (int ni = 0; ni < 4; ++ni)
                #pragma unroll
                for (int r = 0; r < 4; ++r) {
                    int m = mbase + mi * 16 + quad * 4 + r;
                    int n = n0 + ni * 16 + col;
                    ctx_part[((size_t)(ks * BATCH + m)) * D_MODEL + n] = acc[mi][ni][r];
                }
    }
    gg.sync();

    // ---- P4: finalize context (+bc) -> ctxb (bf16). 256 units.
    for (int u = bid; u < 256; u += nb) {
        int i = (u * 256 + tid) * 4;
        float4 s = {0.f, 0.f, 0.f, 0.f};
        #pragma unroll
        for (int ks = 0; ks < 8; ++ks) {
            float4 v = *(const float4*)(ctx_part + (size_t)ks * BATCH * D_MODEL + i);
            s.x += v.x; s.y += v.y; s.z += v.z; s.w += v.w;
        }
        int d = i & (D_MODEL - 1);
        float4 bias = *(const float4*)(bc + d);
        ushort4 hv = {f2bf(s.x + bias.x), f2bf(s.y + bias.y),
                      f2bf(s.z + bias.z), f2bf(s.w + bias.w)};
        *(ushort4*)(ctxb + i) = hv;
    }
    gg.sync();

    // ---- P5: warp+raw GEMM. N=16512 (258 tiles of 64) x KSW k-splits.
    for (int u = bid; u < 258 * KSW; u += nb) {
        int nt = u % 258, ks = u / 258;
        int n0 = nt * 64;
        int k0 = ks * (D_MODEL / KSW);
        const float* Bsrc = (nt < 256) ? (Ww + (size_t)n0 * D_MODEL)
                                       : (room + (size_t)(n0 - NN) * D_MODEL);
        int mbase = w * 32;
        f32x4 acc[2][4] = {};
        for (int kt = 0; kt < (D_MODEL / KSW) / 64; ++kt) {   // 8 iters
            int kb = k0 + kt * 64;
            __syncthreads();
            #pragma unroll
            for (int i = 0; i < 4; ++i) {            // A: 128 x 64 bf16 from ctxb
                int uu = tid + 256 * i;
                int row = uu >> 3, c = uu & 7;
                *(int4*)&A[row * 72 + c * 8] =
                    *(const int4*)(ctxb + (size_t)row * D_MODEL + kb + c * 8);
            }
            #pragma unroll
            for (int i = 0; i < 4; ++i) {            // B: 64 x 64 fp32 -> bf16
                int uu = tid + 256 * i;
                int row = uu >> 4, c = uu & 15;
                float4 v = *(const float4*)(Bsrc + (size_t)row * D_MODEL + kb + c * 4);
                ushort4 hv = {f2bf(v.x), f2bf(v.y), f2bf(v.z), f2bf(v.w)};
                *(ushort4*)&Bt[row * 72 + c * 4] = hv;
            }
            __syncthreads();
            #pragma unroll
            for (int kk = 0; kk < 64; kk += 32) {
                int ko = kk + (lane >> 4) * 8;
                int mr = mbase + (lane & 15);
                bf16x8 a0 = *(const bf16x8*)&A[mr * 72 + ko];
                bf16x8 a1 = *(const bf16x8*)&A[(mr + 16) * 72 + ko];
                #pragma unroll
                for (int ni = 0; ni < 4; ++ni) {
                    bf16x8 bfr = *(const bf16x8*)&Bt[(ni * 16 + (lane & 15)) * 72 + ko];
                    acc[0][ni] = __builtin_amdgcn_mfma_f32_16x16x32_bf16(a0, bfr, acc[0][ni], 0, 0, 0);
                    acc[1][ni] = __builtin_amdgcn_mfma_f32_16x16x32_bf16(a1, bfr, acc[1][ni], 0, 0, 0);
                }
            }
        }
        int col = lane & 15, quad = lane >> 4;
        #pragma unroll
        for (int mi = 0; mi < 2; ++mi)
            #pragma unroll
            for (int ni = 0; ni < 4; ++ni)
                #pragma unroll
                for (int r = 0; r < 4; ++r) {
                    int m = mbase + mi * 16 + quad * 4 + r;
                    int n = n0 + ni * 16 + col;
                    wp[((size_t)(ks * BATCH + m)) * NCOL + n] = acc[mi][ni][r];
                }
    }
    gg.sync();

    // ---- P6: epilogue. 4096 units x 4 waves = 16384 (b,i) rows.
    for (int u = bid; u < 4096; u += nb) {
        int row = u * 4 + w;
        int b = row >> 7, i = row & 127;
        int j0 = lane, j1 = lane + 64;
        int off = i * 128;
        float w0 = 0.f, w1 = 0.f, r0 = 0.f, r1 = 0.f;
        #pragma unroll
        for (int ks = 0; ks < KSW; ++ks) {
            const float* base = wp + (size_t)(ks * BATCH + b) * NCOL;
            w0 += base[off + j0]; w1 += base[off + j1];
            r0 += base[NN + j0];  r1 += base[NN + j1];
        }
        float l0 = adj[off + j0] + 0.1f * (w0 + bw[off + j0]);
        float l1 = adj[off + j1] + 0.1f * (w1 + bw[off + j1]);
        float m = fmaxf(l0, l1);
        #pragma unroll
        for (int o = 32; o; o >>= 1) m = fmaxf(m, __shfl_xor(m, o));
        float p0 = __expf(l0 - m), p1 = __expf(l1 - m);
        float s = p0 + p1;
        float t = p0 * r0 + p1 * r1;
        #pragma unroll
        for (int o = 32; o; o >>= 1) { s += __shfl_xor(s, o); t += __shfl_xor(t, o); }
        if (lane == 0) out[row] = 1.0f / (1.0f + __expf(-(t / s)));
    }
}

// ============================================================================
// Fallback: original verified 6-kernel pipeline (used only if cooperative
// launch is rejected by the runtime / capture).
// ============================================================================
__global__ void k_mean_partial(const float* __restrict__ x, float* __restrict__ part) {
    int bx = blockIdx.x;
    int b = bx >> 4, rem = bx & 15;
    int sc = rem >> 1, dc = rem & 1;
    int d = dc * 1024 + threadIdx.x * 4;
    const float* p = x + ((size_t)(b * SEQ + sc * 64)) * D_MODEL + d;
    float ax = 0.f, ay = 0.f, az = 0.f, aw = 0.f;
    #pragma unroll 8
    for (int s = 0; s < 64; ++s) {
        float4 v = *(const float4*)p;
        ax += v.x; ay += v.y; az += v.z; aw += v.w;
        p += D_MODEL;
    }
    float4 o = {ax, ay, az, aw};
    *(float4*)(part + ((size_t)(sc * BATCH + b)) * D_MODEL + d) = o;
}

__global__ void k_mean_combine(const float* __restrict__ part,
                               unsigned short* __restrict__ meanb) {
    int i = (blockIdx.x * 256 + threadIdx.x) * 4;
    float4 s = {0.f, 0.f, 0.f, 0.f};
    #pragma unroll
    for (int sc = 0; sc < 8; ++sc) {
        float4 v = *(const float4*)(part + (size_t)sc * BATCH * D_MODEL + i);
        s.x += v.x; s.y += v.y; s.z += v.z; s.w += v.w;
    }
    const float inv = 1.0f / (float)SEQ;
    ushort4 hv = {f2bf(s.x * inv), f2bf(s.y * inv), f2bf(s.z * inv), f2bf(s.w * inv)};
    *(ushort4*)(meanb + i) = hv;
}

__launch_bounds__(256)
__global__ void k_ctx_gemm(const unsigned short* __restrict__ meanb,
                           const float* __restrict__ Wc,
                           float* __restrict__ ctx_part) {
    __shared__ short A[128 * 72];
    __shared__ short Bt[64 * 72];
    int bx = blockIdx.x;
    int nt = bx & 31, ks = bx >> 5;
    int n0 = nt * 64;
    int k0 = ks * 256;
    int tid = threadIdx.x, lane = tid & 63, w = tid >> 6;
    int mbase = w * 32;
    f32x4 acc[2][4] = {};
    for (int kt = 0; kt < 4; ++kt) {
        int kb = k0 + kt * 64;
        __syncthreads();
        #pragma unroll
        for (int i = 0; i < 4; ++i) {
            int u = tid + 256 * i;
            int row = u >> 3, c = u & 7;
            *(int4*)&A[row * 72 + c * 8] = *(const int4*)(meanb + (size_t)row * D_MODEL + kb + c * 8);
        }
        #pragma unroll
        for (int i = 0; i < 4; ++i) {
            int u = tid + 256 * i;
            int row = u >> 4, c = u & 15;
            float4 v = *(const float4*)(Wc + (size_t)(n0 + row) * D_MODEL + kb + c * 4);
            ushort4 hv = {f2bf(v.x), f2bf(v.y), f2bf(v.z), f2bf(v.w)};
            *(ushort4*)&Bt[row * 72 + c * 4] = hv;
        }
        __syncthreads();
        #pragma unroll
        for (int kk = 0; kk < 64; kk += 32) {
            int ko = kk + (lane >> 4) * 8;
            int mr = mbase + (lane & 15);
            bf16x8 a0 = *(const bf16x8*)&A[mr * 72 + ko];
            bf16x8 a1 = *(const bf16x8*)&A[(mr + 16) * 72 + ko];
            #pragma unroll
            for (int ni = 0; ni < 4; ++ni) {
                bf16x8 bfr = *(const bf16x8*)&Bt[(ni * 16 + (lane & 15)) * 72 + ko];
                acc[0][ni] = __builtin_amdgcn_mfma_f32_16x16x32_bf16(a0, bfr, acc[0][ni], 0, 0, 0);
                acc[1][ni] = __builtin_amdgcn_mfma_f32_16x16x32_bf16(a1, bfr, acc[1][ni], 0, 0, 0);
            }
        }
    }
    int col = lane & 15, quad = lane >> 4;
    #pragma unroll
    for (int mi = 0; mi < 2; ++mi)
        #pragma unroll
        for (int ni = 0; ni < 4; ++ni)
            #pragma unroll
            for (int r = 0; r < 4; ++r) {
                int m = mbase + mi * 16 + quad * 4 + r;
                int n = n0 + ni * 16 + col;
                ctx_part[((size_t)(ks * BATCH + m)) * D_MODEL + n] = acc[mi][ni][r];
            }
}

__global__ void k_ctx_finalize(const float* __restrict__ ctx_part, const float* __restrict__ bc,
                               unsigned short* __restrict__ ctxb) {
    int i = (blockIdx.x * 256 + threadIdx.x) * 4;
    float4 s = {0.f, 0.f, 0.f, 0.f};
    #pragma unroll
    for (int ks = 0; ks < 8; ++ks) {
        float4 v = *(const float4*)(ctx_part + (size_t)ks * BATCH * D_MODEL + i);
        s.x += v.x; s.y += v.y; s.z += v.z; s.w += v.w;
    }
    int d = i & (D_MODEL - 1);
    float4 bias = *(const float4*)(bc + d);
    ushort4 hv = {f2bf(s.x + bias.x), f2bf(s.y + bias.y), f2bf(s.z + bias.z), f2bf(s.w + bias.w)};
    *(ushort4*)(ctxb + i) = hv;
}

__launch_bounds__(256)
__global__ void k_warp_gemm(const unsigned short* __restrict__ ctxb,
                            const float* __restrict__ Ww,
                            const float* __restrict__ room,
                            float* __restrict__ wp) {
    __shared__ short A[128 * 72];
    __shared__ short Bt[64 * 72];
    int bx = blockIdx.x;
    int nt = bx % 258, ks = bx / 258;
    int n0 = nt * 64;
    int k0 = ks * 1024;
    const float* Bsrc = (nt < 256) ? (Ww + (size_t)n0 * D_MODEL)
                                   : (room + (size_t)(n0 - NN) * D_MODEL);
    int tid = threadIdx.x, lane = tid & 63, w = tid >> 6;
    int mbase = w * 32;
    f32x4 acc[2][4] = {};
    for (int kt = 0; kt < 16; ++kt) {
        int kb = k0 + kt * 64;
        __syncthreads();
        #pragma unroll
        for (int i = 0; i < 4; ++i) {
            int u = tid + 256 * i;
            int row = u >> 3, c = u & 7;
            *(int4*)&A[row * 72 + c * 8] = *(const int4*)(ctxb + (size_t)row * D_MODEL + kb + c * 8);
        }
        #pragma unroll
        for (int i = 0; i < 4; ++i) {
            int u = tid + 256 * i;
            int row = u >> 4, c = u & 15;
            float4 v = *(const float4*)(Bsrc + (size_t)row * D_MODEL + kb + c * 4);
            ushort4 hv = {f2bf(v.x), f2bf(v.y), f2bf(v.z), f2bf(v.w)};
            *(ushort4*)&Bt[row * 72 + c * 4] = hv;
        }
        __syncthreads();
        #pragma unroll
        for (int kk = 0; kk < 64; kk += 32) {
            int ko = kk + (lane >> 4) * 8;
            int mr = mbase + (lane & 15);
            bf16x8 a0 = *(const bf16x8*)&A[mr * 72 + ko];
            bf16x8 a1 = *(const bf16x8*)&A[(mr + 16) * 72 + ko];
            #pragma unroll
            for (int ni = 0; ni < 4; ++ni) {
                bf16x8 bfr = *(const bf16x8*)&Bt[(ni * 16 + (lane & 15)) * 72 + ko];
                acc[0][ni] = __builtin_amdgcn_mfma_f32_16x16x32_bf16(a0, bfr, acc[0][ni], 0, 0, 0);
                acc[1][ni] = __builtin_amdgcn_mfma_f32_16x16x32_bf16(a1, bfr, acc[1][ni], 0, 0, 0);
            }
        }
    }
    int col = lane & 15, quad = lane >> 4;
    #pragma unroll
    for (int mi = 0; mi < 2; ++mi)
        #pragma unroll
        for (int ni = 0; ni < 4; ++ni)
            #pragma unroll
            for (int r = 0; r < 4; ++r) {
                int m = mbase + mi * 16 + quad * 4 + r;
                int n = n0 + ni * 16 + col;
                wp[((size_t)(ks * BATCH + m)) * NCOL + n] = acc[mi][ni][r];
            }
}

__global__ void k_epilogue(const float* __restrict__ wp, const float* __restrict__ bw,
                           const float* __restrict__ adj, float* __restrict__ out) {
    int tid = threadIdx.x, lane = tid & 63, w = tid >> 6;
    int row = blockIdx.x * 4 + w;
    int b = row >> 7, i = row & 127;
    int j0 = lane, j1 = lane + 64;
    size_t b0 = (size_t)b * NCOL;
    size_t b1 = (size_t)(BATCH + b) * NCOL;
    int off = i * 128;
    float w0 = wp[b0 + off + j0] + wp[b1 + off + j0];
    float w1 = wp[b0 + off + j1] + wp[b1 + off + j1];
    float r0 = wp[b0 + NN + j0] + wp[b1 + NN + j0];
    float r1 = wp[b0 + NN + j1] + wp[b1 + NN + j1];
    float l0 = adj[off + j0] + 0.1f * (w0 + bw[off + j0]);
    float l1 = adj[off + j1] + 0.1f * (w1 + bw[off + j1]);
    float m = fmaxf(l0, l1);
    #pragma unroll
    for (int o = 32; o; o >>= 1) m = fmaxf(m, __shfl_xor(m, o));
    float p0 = __expf(l0 - m), p1 = __expf(l1 - m);
    float s = p0 + p1;
    float t = p0 * r0 + p1 * r1;
    #pragma unroll
    for (int o = 32; o; o >>= 1) { s += __shfl_xor(s, o); t += __shfl_xor(t, o); }
    if (lane == 0) out[row] = 1.0f / (1.0f + __expf(-(t / s)));
}

extern "C" void kernel_launch(void* const* d_in, const int* in_sizes, int n_in,
                              void* d_out, int out_size, void* d_ws, size_t ws_size,
                              hipStream_t stream) {
    (void)in_sizes; (void)n_in; (void)out_size; (void)ws_size;
    const float* x    = (const float*)d_in[0];
    const float* room = (const float*)d_in[1];
    const float* Wc   = (const float*)d_in[2];
    const float* bc   = (const float*)d_in[3];
    const float* Ww   = (const float*)d_in[4];
    const float* bw   = (const float*)d_in[5];
    const float* adj  = (const float*)d_in[6];
    float* out = (float*)d_out;
    char* ws = (char*)d_ws;
    const size_t MB = 1u << 20;
    float*          part     = (float*)(ws + 0);                 // 8 MB
    unsigned short* meanb    = (unsigned short*)(ws + 8 * MB);   // 512 KB
    float*          ctx_part = (float*)(ws + 9 * MB);            // 8 MB
    unsigned short* ctxb     = (unsigned short*)(ws + 17 * MB);  // 512 KB
    float*          wp       = (float*)(ws + 18 * MB);           // KSW*128*16512*4 ~= 32.3 MB

    // Decide cooperative grid once (pure occupancy query, capture-safe).
    static int coop_grid = -1;
    if (coop_grid < 0) {
        int nbpc = 0;
        if (hipOccupancyMaxActiveBlocksPerMultiprocessor(
                &nbpc, (const void*)k_fused, 256, 0) != hipSuccess || nbpc < 1) {
            coop_grid = 0;   // occupancy unknown -> use fallback path
        } else {
            int g = nbpc * 256;            // 256 CUs on MI355X
            coop_grid = (g < 1024) ? g : 1024;
        }
    }

    bool launched = false;
    if (coop_grid > 0) {
        void* args[] = {
            (void*)&x, (void*)&room, (void*)&Wc, (void*)&bc, (void*)&Ww,
            (void*)&bw, (void*)&adj, (void*)&out,
            (void*)&part, (void*)&meanb, (void*)&ctx_part, (void*)&ctxb, (void*)&wp
        };
        hipError_t err = hipLaunchCooperativeKernel((const void*)k_fused,
                                                    dim3(coop_grid), dim3(256),
                                                    args, 0, stream);
        if (err == hipSuccess) {
            launched = true;
        } else {
            coop_grid = 0;   // never retry; fall back permanently
        }
    }

    if (!launched) {
        hipLaunchKernelGGL(k_mean_partial, dim3(2048), dim3(256), 0, stream, x, part);
        hipLaunchKernelGGL(k_mean_combine, dim3(256), dim3(256), 0, stream, part, meanb);
        hipLaunchKernelGGL(k_ctx_gemm, dim3(256), dim3(256), 0, stream, meanb, Wc, ctx_part);
        hipLaunchKernelGGL(k_ctx_finalize, dim3(256), dim3(256), 0, stream, ctx_part, bc, ctxb);
        hipLaunchKernelGGL(k_warp_gemm, dim3(516), dim3(256), 0, stream, ctxb, Ww, room, wp);
        hipLaunchKernelGGL(k_epilogue, dim3(4096), dim3(256), 0, stream, wp, bw, adj, out);
    }
}

// Round 2
// 909.448 us; speedup vs baseline: 1.2009x; 1.2009x over previous
//
#include <hip/hip_runtime.h>
#include <stdint.h>

#define D_MODEL 2048
#define N_ROOMS 128
#define BATCH   128
#define SEQ     512
#define NN      (N_ROOMS * N_ROOMS)   // 16384

typedef short bf16x8 __attribute__((ext_vector_type(8)));
typedef float f32x4  __attribute__((ext_vector_type(4)));

__device__ __forceinline__ unsigned short f2bf(float f) {
    union { float f; uint32_t u; } c; c.f = f;
    uint32_t u = c.u;
    uint32_t r = (u + 0x7fffu + ((u >> 16) & 1u)) >> 16;  // RNE
    return (unsigned short)r;
}

// ---------------------------------------------------------------- mean over S
// grid 2048 = B(128) x sc(8) x dc(2); 256 thr; each thread one float4 of d,
// 64 s-steps. Writes partial sums part[sc][b][d].
__global__ void k_mean_partial(const float* __restrict__ x, float* __restrict__ part) {
    int bx = blockIdx.x;
    int b = bx >> 4, rem = bx & 15;
    int sc = rem >> 1, dc = rem & 1;
    int d = dc * 1024 + threadIdx.x * 4;
    const float* p = x + ((size_t)(b * SEQ + sc * 64)) * D_MODEL + d;
    float ax = 0.f, ay = 0.f, az = 0.f, aw = 0.f;
    #pragma unroll 8
    for (int s = 0; s < 64; ++s) {
        float4 v = *(const float4*)p;
        ax += v.x; ay += v.y; az += v.z; aw += v.w;
        p += D_MODEL;
    }
    float4 o = {ax, ay, az, aw};
    *(float4*)(part + ((size_t)(sc * BATCH + b)) * D_MODEL + d) = o;
}

// ------------------------------------------------- combine mean -> bf16 only
__global__ void k_mean_combine(const float* __restrict__ part,
                               unsigned short* __restrict__ meanb) {
    int i = (blockIdx.x * 256 + threadIdx.x) * 4;   // 256 blocks covers B*D
    float4 s = {0.f, 0.f, 0.f, 0.f};
    #pragma unroll
    for (int sc = 0; sc < 8; ++sc) {
        float4 v = *(const float4*)(part + (size_t)sc * BATCH * D_MODEL + i);
        s.x += v.x; s.y += v.y; s.z += v.z; s.w += v.w;
    }
    const float inv = 1.0f / (float)SEQ;
    ushort4 hv = {f2bf(s.x * inv), f2bf(s.y * inv), f2bf(s.z * inv), f2bf(s.w * inv)};
    *(ushort4*)(meanb + i) = hv;
}

// ---------------------------------------------------- context GEMM (bf16)
// C[b][d] = sum_k mean[b][k] * Wc[d][k];  M=128, N=2048, K=2048.
// tile 128x64, BK=64, K-split 8 -> grid 256. Partials to ctx_part[ks][b][d].
__launch_bounds__(256)
__global__ void k_ctx_gemm(const unsigned short* __restrict__ meanb,
                           const float* __restrict__ Wc,
                           float* __restrict__ ctx_part) {
    __shared__ short A[128 * 72];
    __shared__ short Bt[64 * 72];
    int bx = blockIdx.x;
    int nt = bx & 31, ks = bx >> 5;
    int n0 = nt * 64;
    int k0 = ks * 256;
    int tid = threadIdx.x, lane = tid & 63, w = tid >> 6;
    int mbase = w * 32;
    f32x4 acc[2][4] = {};
    for (int kt = 0; kt < 4; ++kt) {
        int kb = k0 + kt * 64;
        __syncthreads();
        #pragma unroll
        for (int i = 0; i < 4; ++i) {            // A: 128 rows x 64 bf16
            int u = tid + 256 * i;
            int row = u >> 3, c = u & 7;
            *(int4*)&A[row * 72 + c * 8] = *(const int4*)(meanb + (size_t)row * D_MODEL + kb + c * 8);
        }
        #pragma unroll
        for (int i = 0; i < 4; ++i) {            // B: 64 rows x 64 fp32 -> bf16
            int u = tid + 256 * i;
            int row = u >> 4, c = u & 15;
            float4 v = *(const float4*)(Wc + (size_t)(n0 + row) * D_MODEL + kb + c * 4);
            ushort4 hv = {f2bf(v.x), f2bf(v.y), f2bf(v.z), f2bf(v.w)};
            *(ushort4*)&Bt[row * 72 + c * 4] = hv;
        }
        __syncthreads();
        #pragma unroll
        for (int kk = 0; kk < 64; kk += 32) {
            int ko = kk + (lane >> 4) * 8;
            int mr = mbase + (lane & 15);
            bf16x8 a0 = *(const bf16x8*)&A[mr * 72 + ko];
            bf16x8 a1 = *(const bf16x8*)&A[(mr + 16) * 72 + ko];
            #pragma unroll
            for (int ni = 0; ni < 4; ++ni) {
                bf16x8 bfr = *(const bf16x8*)&Bt[(ni * 16 + (lane & 15)) * 72 + ko];
                acc[0][ni] = __builtin_amdgcn_mfma_f32_16x16x32_bf16(a0, bfr, acc[0][ni], 0, 0, 0);
                acc[1][ni] = __builtin_amdgcn_mfma_f32_16x16x32_bf16(a1, bfr, acc[1][ni], 0, 0, 0);
            }
        }
    }
    int col = lane & 15, quad = lane >> 4;
    #pragma unroll
    for (int mi = 0; mi < 2; ++mi)
        #pragma unroll
        for (int ni = 0; ni < 4; ++ni)
            #pragma unroll
            for (int r = 0; r < 4; ++r) {
                int m = mbase + mi * 16 + quad * 4 + r;    // b
                int n = n0 + ni * 16 + col;                // d
                ctx_part[((size_t)(ks * BATCH + m)) * D_MODEL + n] = acc[mi][ni][r];
            }
}

// -------------------------------------- finalize context (+bc) -> bf16 only
__global__ void k_ctx_finalize(const float* __restrict__ ctx_part, const float* __restrict__ bc,
                               unsigned short* __restrict__ ctxb) {
    int i = (blockIdx.x * 256 + threadIdx.x) * 4;
    float4 s = {0.f, 0.f, 0.f, 0.f};
    #pragma unroll
    for (int ks = 0; ks < 8; ++ks) {
        float4 v = *(const float4*)(ctx_part + (size_t)ks * BATCH * D_MODEL + i);
        s.x += v.x; s.y += v.y; s.z += v.z; s.w += v.w;
    }
    int d = i & (D_MODEL - 1);
    float4 bias = *(const float4*)(bc + d);
    ushort4 hv = {f2bf(s.x + bias.x), f2bf(s.y + bias.y), f2bf(s.z + bias.z), f2bf(s.w + bias.w)};
    *(ushort4*)(ctxb + i) = hv;
}

// ------------------- fused warp+raw GEMM + softmax epilogue -----------------
// grid 256: i = bid & 127 (room row), half = bid >> 7 (b-half of 64).
// Block computes S_w[b][j] = ctx[b]·Ww[i*128+j] and S_r[b][j] = ctx[b]·room[j]
// for b in [half*64, half*64+64), j in [0,128), full K=2048, then
// out[b][i] = sigmoid( sum_j softmax_j(adj[i][j]+0.1*(S_w+bw)) * S_r[b][j] ).
// No wp buffer: 51 MB of HBM round-trip eliminated vs the 2-kernel version.
// Pairing (bid, bid+128): 128 % 8 == 0 -> same XCD, Ww lines shared in L2.
__launch_bounds__(512)
__global__ void k_wepi(const unsigned short* __restrict__ ctxb,
                       const float* __restrict__ Ww,
                       const float* __restrict__ room,
                       const float* __restrict__ bw,
                       const float* __restrict__ adj,
                       float* __restrict__ out) {
    __shared__ short A[64 * 72];        // 64 b-rows x 64 k (bf16)
    __shared__ short Bt[256 * 72];      // rows 0..127: Ww[i*128+j]; 128..255: room[j]
    __shared__ float red[3][4][64];     // [max/sum/dot][wn][row]
    const int i_room = blockIdx.x & 127;
    const int half   = blockIdx.x >> 7;
    const int tid = threadIdx.x, lane = tid & 63, w = tid >> 6;
    const int wm = w & 1, wn = w >> 1;          // 2 M-quads x 4 N-quads
    const int mbase = wm * 32, jbase = wn * 32;
    const size_t wwbase = (size_t)i_room * 128 * D_MODEL;

    f32x4 aw[2][2] = {};   // warp scores  [mi][ni]
    f32x4 ar[2][2] = {};   // raw  scores  [mi][ni]

    for (int kt = 0; kt < 32; ++kt) {
        int kb = kt * 64;
        __syncthreads();
        {   // A: 64 x 64 bf16 from ctxb (1 int4 per thread)
            int row = tid >> 3, c = tid & 7;
            *(int4*)&A[row * 72 + c * 8] =
                *(const int4*)(ctxb + (size_t)(half * 64 + row) * D_MODEL + kb + c * 8);
        }
        #pragma unroll
        for (int it = 0; it < 8; ++it) {   // B: 256 x 64 fp32 -> bf16
            int u = tid + 512 * it;
            int row = u >> 4, c = u & 15;
            const float* src = (row < 128) ? (Ww + wwbase + (size_t)row * D_MODEL)
                                           : (room + (size_t)(row - 128) * D_MODEL);
            float4 v = *(const float4*)(src + kb + c * 4);
            ushort4 hv = {f2bf(v.x), f2bf(v.y), f2bf(v.z), f2bf(v.w)};
            *(ushort4*)&Bt[row * 72 + c * 4] = hv;
        }
        __syncthreads();
        #pragma unroll
        for (int kk = 0; kk < 64; kk += 32) {
            int ko = kk + (lane >> 4) * 8;
            int mr = mbase + (lane & 15);
            bf16x8 a0 = *(const bf16x8*)&A[mr * 72 + ko];
            bf16x8 a1 = *(const bf16x8*)&A[(mr + 16) * 72 + ko];
            #pragma unroll
            for (int ni = 0; ni < 2; ++ni) {
                int br = jbase + ni * 16 + (lane & 15);
                bf16x8 bW = *(const bf16x8*)&Bt[br * 72 + ko];
                bf16x8 bR = *(const bf16x8*)&Bt[(128 + br) * 72 + ko];
                aw[0][ni] = __builtin_amdgcn_mfma_f32_16x16x32_bf16(a0, bW, aw[0][ni], 0, 0, 0);
                aw[1][ni] = __builtin_amdgcn_mfma_f32_16x16x32_bf16(a1, bW, aw[1][ni], 0, 0, 0);
                ar[0][ni] = __builtin_amdgcn_mfma_f32_16x16x32_bf16(a0, bR, ar[0][ni], 0, 0, 0);
                ar[1][ni] = __builtin_amdgcn_mfma_f32_16x16x32_bf16(a1, bR, ar[1][ni], 0, 0, 0);
            }
        }
    }

    // ---- epilogue: softmax over j (128) per (b,i), dot with raw, sigmoid.
    const int col = lane & 15, quad = lane >> 4;
    float adj0 = adj[i_room * 128 + jbase + col];
    float adj1 = adj[i_room * 128 + jbase + 16 + col];
    float bw0  = bw[i_room * 128 + jbase + col];
    float bw1  = bw[i_room * 128 + jbase + 16 + col];

    float l0[2][4], l1[2][4];
    // per-row partial max over this wave's 32 j's (16 col-lanes x 2 ni)
    #pragma unroll
    for (int mi = 0; mi < 2; ++mi)
        #pragma unroll
        for (int r = 0; r < 4; ++r) {
            l0[mi][r] = adj0 + 0.1f * (aw[mi][0][r] + bw0);
            l1[mi][r] = adj1 + 0.1f * (aw[mi][1][r] + bw1);
            float m2 = fmaxf(l0[mi][r], l1[mi][r]);
            #pragma unroll
            for (int o = 1; o < 16; o <<= 1) m2 = fmaxf(m2, __shfl_xor(m2, o));
            if (col == 0) red[0][wn][mbase + mi * 16 + quad * 4 + r] = m2;
        }
    __syncthreads();
    #pragma unroll
    for (int mi = 0; mi < 2; ++mi)
        #pragma unroll
        for (int r = 0; r < 4; ++r) {
            int rl = mbase + mi * 16 + quad * 4 + r;
            float m = fmaxf(fmaxf(red[0][0][rl], red[0][1][rl]),
                            fmaxf(red[0][2][rl], red[0][3][rl]));
            float p0 = __expf(l0[mi][r] - m);
            float p1 = __expf(l1[mi][r] - m);
            float s = p0 + p1;
            float t = p0 * ar[mi][0][r] + p1 * ar[mi][1][r];
            #pragma unroll
            for (int o = 1; o < 16; o <<= 1) { s += __shfl_xor(s, o); t += __shfl_xor(t, o); }
            if (col == 0) { red[1][wn][rl] = s; red[2][wn][rl] = t; }
        }
    __syncthreads();
    if (wn == 0 && col == 0) {
        #pragma unroll
        for (int mi = 0; mi < 2; ++mi)
            #pragma unroll
            for (int r = 0; r < 4; ++r) {
                int rl = mbase + mi * 16 + quad * 4 + r;
                float s = red[1][0][rl] + red[1][1][rl] + red[1][2][rl] + red[1][3][rl];
                float t = red[2][0][rl] + red[2][1][rl] + red[2][2][rl] + red[2][3][rl];
                out[(size_t)(half * 64 + rl) * N_ROOMS + i_room] =
                    1.0f / (1.0f + __expf(-(t / s)));
            }
    }
}

extern "C" void kernel_launch(void* const* d_in, const int* in_sizes, int n_in,
                              void* d_out, int out_size, void* d_ws, size_t ws_size,
                              hipStream_t stream) {
    (void)in_sizes; (void)n_in; (void)out_size; (void)ws_size;
    const float* x    = (const float*)d_in[0];
    const float* room = (const float*)d_in[1];
    const float* Wc   = (const float*)d_in[2];
    const float* bc   = (const float*)d_in[3];
    const float* Ww   = (const float*)d_in[4];
    const float* bw   = (const float*)d_in[5];
    const float* adj  = (const float*)d_in[6];
    float* out = (float*)d_out;
    char* ws = (char*)d_ws;
    const size_t MB = 1u << 20;
    float*          part     = (float*)(ws + 0);                      // 8 MB
    unsigned short* meanb    = (unsigned short*)(ws + 8 * MB);        // 512 KB
    float*          ctx_part = (float*)(ws + 9 * MB);                 // 8 MB
    unsigned short* ctxb     = (unsigned short*)(ws + 17 * MB);       // 512 KB

    hipLaunchKernelGGL(k_mean_partial, dim3(2048), dim3(256), 0, stream, x, part);
    hipLaunchKernelGGL(k_mean_combine, dim3(256), dim3(256), 0, stream, part, meanb);
    hipLaunchKernelGGL(k_ctx_gemm, dim3(256), dim3(256), 0, stream, meanb, Wc, ctx_part);
    hipLaunchKernelGGL(k_ctx_finalize, dim3(256), dim3(256), 0, stream, ctx_part, bc, ctxb);
    hipLaunchKernelGGL(k_wepi, dim3(256), dim3(512), 0, stream, ctxb, Ww, room, bw, adj, out);
}